// Round 9
// baseline (71.333 us; speedup 1.0000x reference)
//
#include <hip/hip_runtime.h>
#include <hip/hip_bf16.h>
#include <math.h>

// BlockSoftmaxLinearHybrid: B=2,H=16,L=4096,D=64,F=64,S=64
constexpr int Hc = 16, Lc = 4096, Dc = 64;
constexpr int F2 = 128;
constexpr int NBLK = 2048;         // 32 bh * 64 tiles
constexpr float EPSf = 1e-6f;
constexpr float SCALE = 0.125f;    // D^-0.5

typedef short short8 __attribute__((ext_vector_type(8)));     // 8 bf16 MFMA A/B frag
typedef float f32x4 __attribute__((ext_vector_type(4)));      // MFMA C/D frag
typedef unsigned short ushort;
typedef unsigned int uint;
typedef ushort ushort4v __attribute__((ext_vector_type(4)));

__device__ inline ushort f2bf(float x) {           // native cvt (fuses to v_cvt_pk_bf16_f32)
    return __builtin_bit_cast(ushort, __float2bfloat16(x));
}
__device__ inline float bf2f(ushort h) {
    return __builtin_bit_cast(float, ((unsigned)h) << 16);
}
__device__ inline f32x4 zero4() { f32x4 z = {0.f, 0.f, 0.f, 0.f}; return z; }

__device__ inline f32x4 mfma(short8 a, short8 b, f32x4 c) {
    return __builtin_amdgcn_mfma_f32_16x16x32_bf16(a, b, c, 0, 0, 0);
}

// async 16B global->LDS DMA (per-lane global addr, wave-uniform LDS base + lane*16)
__device__ inline void dma16(const void* g, void* l) {
    __builtin_amdgcn_global_load_lds(
        (const __attribute__((address_space(1))) unsigned int*)g,
        (__attribute__((address_space(3))) unsigned int*)l, 16, 0, 0);
}

// LDS fragment read, XOR-swizzled 16B chunks (T2)
__device__ inline short8 ldfrag(const char* L, int row, int chunk, int rowbytes, int mask) {
    return *(const short8*)(L + row * rowbytes + ((chunk * 16) ^ ((row & mask) << 4)));
}

// Direct global frag: 8 consecutive fp32 at [row][chunk*8] of row-major [.][64] -> bf16
__device__ inline short8 gfrag_f32(const float* __restrict__ base, int row, int chunk) {
    const float4* p = (const float4*)(base + row * 64 + chunk * 8);
    float4 a = p[0], b = p[1];
    short8 r;
    r[0] = (short)f2bf(a.x); r[1] = (short)f2bf(a.y); r[2] = (short)f2bf(a.z); r[3] = (short)f2bf(a.w);
    r[4] = (short)f2bf(b.x); r[5] = (short)f2bf(b.y); r[6] = (short)f2bf(b.z); r[7] = (short)f2bf(b.w);
    return r;
}
// Direct global frag from bf16 row-major [.][rowlen]
__device__ inline short8 gfrag_bf16(const ushort* __restrict__ base, int row, int chunk, int rowlen) {
    return *(const short8*)(base + row * rowlen + chunk * 8);
}

// coalesced transpose stage: [64][64] fp32 -> dst[j][i] bf16 swz (mask 7)
__device__ inline void stage_tr(const float* __restrict__ src, char* dst, int t) {
    int j = t & 63, g = t >> 6;
    #pragma unroll
    for (int i = 0; i < 4; ++i) {
        int i0 = g * 4 + i * 16;
        ushort4v hv;
        #pragma unroll
        for (int jj = 0; jj < 4; ++jj) hv[jj] = f2bf(src[(i0 + jj) * 64 + j]);
        *(ushort4v*)(dst + j * 128 + ((2 * i0) ^ ((j & 7) << 4))) = hv;
    }
}

// ---------------------------------------------------------------------------
// passW: Wt[h][f][d] = bf16(W[h][d][f])
// ---------------------------------------------------------------------------
__global__ __launch_bounds__(256) void passW(const float* __restrict__ W,
                                             ushort* __restrict__ Wt)
{
    const int h = blockIdx.x, t = threadIdx.x;
    const int f = t & 63, g = t >> 6;
    const float* src = W + (long)h * 4096;
    ushort* dst = Wt + (long)h * 4096;
    #pragma unroll
    for (int i = 0; i < 16; ++i) {
        int d = g * 16 + i;
        dst[f * 64 + d] = f2bf(src[d * 64 + f]);
    }
}

// ---------------------------------------------------------------------------
// passA: phi(k); dSt[d][f] = v^T @ phi_k -> wsS bf16; dZ[f] -> wsZ fp32;
//        dump swizzled vT bytes -> wsV and swizzled k bf16 -> wsK
//        (passC DMAs both back, bit-identical). ONE barrier.
// ---------------------------------------------------------------------------
__global__ __launch_bounds__(256) void passA(const float* __restrict__ K,
                                             const float* __restrict__ V,
                                             const ushort* __restrict__ Wt,
                                             ushort* __restrict__ wsS,
                                             float* __restrict__ wsZ,
                                             char* __restrict__ wsV,
                                             char* __restrict__ wsK)
{
    __shared__ __align__(16) char lds[26624];
    char* vT = lds;                      // [64 d][64 s] swz7
    char* pT = lds + 8192;               // [128 f][64 s] swz7
    float* Zp = (float*)(lds + 24576);   // [4 wv][128 f]

    const int t = threadIdx.x, wv = t >> 6, l = t & 63, lr = l & 15, lg = l >> 4;
    const int bid = blockIdx.x, bh = bid >> 6, h = bh & (Hc - 1);
    const long base = (long)bh * (Lc * Dc) + (long)(bid & 63) * (64 * Dc);

    stage_tr(V + base, vT, t);

    const float* kp = K + base;
    const ushort* wt = Wt + (long)h * 4096;

    // u = k @ W : A = k rows (own-wave rows, global), B = Wt rows (global bf16)
    short8 ak0 = gfrag_f32(kp, 16 * wv + lr, lg);
    short8 ak1 = gfrag_f32(kp, 16 * wv + lr, 4 + lg);

    // dump k bf16 in swizzled byte order (passC DMAs linearly -> swz LDS, T21)
    {
        char* kd = wsK + (long)bid * 8192;
        const int srow = 16 * wv + lr;
        *(short8*)(kd + srow * 128 + ((lg * 16) ^ ((srow & 7) << 4))) = ak0;
        *(short8*)(kd + srow * 128 + (((4 + lg) * 16) ^ ((srow & 7) << 4))) = ak1;
    }

    f32x4 u0[4];
    #pragma unroll
    for (int tf = 0; tf < 4; ++tf) u0[tf] = zero4();
    #pragma unroll
    for (int tf = 0; tf < 4; ++tf) {
        u0[tf] = mfma(ak0, gfrag_bf16(wt, tf * 16 + lr, lg, 64), u0[tf]);
        u0[tf] = mfma(ak1, gfrag_bf16(wt, tf * 16 + lr, 4 + lg, 64), u0[tf]);
    }

    // dual softmax over f (no max-sub: softmax invariant, |u| small)
    float pp[4][4], pn[4][4];
    float zpa[4] = {0.f,0.f,0.f,0.f}, zna[4] = {0.f,0.f,0.f,0.f};
    #pragma unroll
    for (int r = 0; r < 4; ++r) {
        float sp = 0.f, sn = 0.f;
        #pragma unroll
        for (int tf = 0; tf < 4; ++tf) {
            pp[tf][r] = __expf(u0[tf][r]);  sp += pp[tf][r];
            pn[tf][r] = __expf(-u0[tf][r]); sn += pn[tf][r];
        }
        #pragma unroll
        for (int m = 1; m < 16; m <<= 1) { sp += __shfl_xor(sp, m, 16); sn += __shfl_xor(sn, m, 16); }
        float rp = 1.f / sp, rn = 1.f / sn;
        #pragma unroll
        for (int tf = 0; tf < 4; ++tf) {
            pp[tf][r] *= rp; pn[tf][r] *= rn;
            zpa[tf] += pp[tf][r]; zna[tf] += pn[tf][r];
        }
    }

    // packed phi_k^T writes: pT[f][s], 4 consecutive s -> ds_write_b64
    const int s0 = 16 * wv + lg * 4;
    #pragma unroll
    for (int tf = 0; tf < 4; ++tf) {
        int f = tf * 16 + lr;
        ushort4v hp, hn;
        #pragma unroll
        for (int r = 0; r < 4; ++r) { hp[r] = f2bf(pp[tf][r]); hn[r] = f2bf(pn[tf][r]); }
        *(ushort4v*)(pT + f * 128 + ((2 * s0) ^ ((f & 7) << 4))) = hp;
        int fn = 64 + f;
        *(ushort4v*)(pT + fn * 128 + ((2 * s0) ^ ((fn & 7) << 4))) = hn;
    }
    // Z partials (per wave)
    #pragma unroll
    for (int tf = 0; tf < 4; ++tf) {
        zpa[tf] += __shfl_xor(zpa[tf], 16); zpa[tf] += __shfl_xor(zpa[tf], 32);
        zna[tf] += __shfl_xor(zna[tf], 16); zna[tf] += __shfl_xor(zna[tf], 32);
    }
    if (l < 16) {
        #pragma unroll
        for (int tf = 0; tf < 4; ++tf) {
            Zp[wv * 128 + tf * 16 + lr]      = zpa[tf];
            Zp[wv * 128 + 64 + tf * 16 + lr] = zna[tf];
        }
    }
    __syncthreads();

    // dump swizzled vT bytes (bit-identical reuse by passC via DMA)
    {
        const short8* vs = (const short8*)vT;
        short8* vd = (short8*)(wsV + (long)bid * 8192);
        vd[t]       = vs[t];
        vd[t + 256] = vs[t + 256];
    }

    // dSt[d][f] = v^T @ phi_k
    short8 av0 = ldfrag(vT, 16 * wv + lr, lg, 128, 7);
    short8 av1 = ldfrag(vT, 16 * wv + lr, 4 + lg, 128, 7);
    f32x4 acc[8];
    #pragma unroll
    for (int tf = 0; tf < 8; ++tf) acc[tf] = zero4();
    __builtin_amdgcn_s_setprio(1);
    #pragma unroll
    for (int tf = 0; tf < 8; ++tf) {
        acc[tf] = mfma(av0, ldfrag(pT, tf * 16 + lr, lg, 128, 7), acc[tf]);
        acc[tf] = mfma(av1, ldfrag(pT, tf * 16 + lr, 4 + lg, 128, 7), acc[tf]);
    }
    __builtin_amdgcn_s_setprio(0);
    ushort* o = wsS + (long)bid * (F2 * Dc);
    #pragma unroll
    for (int tf = 0; tf < 8; ++tf)
        #pragma unroll
        for (int r = 0; r < 4; ++r) {
            int d = 16 * wv + lg * 4 + r;
            o[d * 128 + tf * 16 + lr] = f2bf(acc[tf][r]);
        }

    if (t < 128)
        wsZ[(long)bid * F2 + t] = Zp[t] + Zp[128 + t] + Zp[256 + t] + Zp[384 + t];
}

// ---------------------------------------------------------------------------
// passB: exclusive prefix over n per bh. 2048 wave-slices (4B/lane), all 64
// tile-loads batched in flight. grid = 512 S-blocks + 32 Z-blocks.
// ---------------------------------------------------------------------------
__global__ __launch_bounds__(256) void passB(uint* __restrict__ wsSu,
                                             float* __restrict__ wsZ)
{
    const int t = threadIdx.x;
    if (blockIdx.x >= 512) {                 // Z prefix
        const int bh = blockIdx.x - 512;
        if (t < 128) {
            float zc = 0.f, zb[32];
            #pragma unroll
            for (int h2 = 0; h2 < 2; ++h2) {
                float* zp = wsZ + ((long)bh * 64 + h2 * 32) * 128 + t;
                #pragma unroll
                for (int i = 0; i < 32; ++i) zb[i] = zp[i * 128];
                #pragma unroll
                for (int i = 0; i < 32; ++i) { float x = zb[i]; zp[i * 128] = zc; zc += x; }
            }
        }
        return;
    }
    const int bh = blockIdx.x >> 4;
    const int slice = (blockIdx.x & 15) * 4 + (t >> 6);    // 0..63 per bh
    const int lane = t & 63;
    uint* p = wsSu + (long)bh * 64 * 4096 + slice * 64 + lane;
    uint buf[64];
    #pragma unroll
    for (int i = 0; i < 64; ++i) buf[i] = p[i * 4096];
    float c0 = 0.f, c1 = 0.f;
    #pragma unroll
    for (int i = 0; i < 64; ++i) {
        uint x = buf[i];
        uint pc = ((uint)f2bf(c1) << 16) | (uint)f2bf(c0);
        p[i * 4096] = pc;
        c0 += bf2f((ushort)(x & 0xffffu));
        c1 += bf2f((ushort)(x >> 16));
    }
}

// ---------------------------------------------------------------------------
// passC: ZERO register staging — kR/vT/St all via async DMA; q own-row frags;
// Wt L2-hot frags; wsZ hoisted to early loads. phi (16K) overlays kR+vT after
// they die. 2 barriers, 40K LDS (4 blocks/CU). setprio around MFMA clusters.
// ---------------------------------------------------------------------------
__global__ __launch_bounds__(256) void passC(const float* __restrict__ Q,
                                             const ushort* __restrict__ Wt,
                                             const float* __restrict__ Alpha,
                                             const ushort* __restrict__ wsS,
                                             const float* __restrict__ wsZ,
                                             const char* __restrict__ wsV,
                                             const char* __restrict__ wsK,
                                             float* __restrict__ Out)
{
    __shared__ __align__(16) char lds[40960];
    char* kR    = lds;                   // 8K  [64 t][64 d] swz7  (DMA; dead after scores)
    char* vT    = lds + 8192;            // 8K  [64 d][64 t] swz7  (DMA; dead after a@v)
    char* St    = lds + 16384;           // 16K [64 d][128 f] swz15 (DMA; live to end)
    char* aAB   = lds + 32768;           // 8K  [64 s][64 t] swz7  (wave-local rows)
    char* phiAB = lds;                   // 16K [64 s][128 f] swz15 (overlay after barrier B)

    const int t = threadIdx.x, wv = t >> 6, l = t & 63, lr = l & 15, lg = l >> 4;
    const int bid = blockIdx.x, bh = bid >> 6, h = bh & (Hc - 1);
    const long base = (long)bh * (Lc * Dc) + (long)(bid & 63) * (64 * Dc);
    const int s = 16 * wv + lr;          // this lane's owned row

    // ---- async DMA staging (issue first; drains at barrier A)
    {
        const char* kg = wsK + (long)bid * 8192;
        const char* vg = wsV + (long)bid * 8192;
        #pragma unroll
        for (int i = 0; i < 2; ++i) {
            int jb = wv * 128 + i * 64;
            dma16(kg + (long)(jb + l) * 16, kR + jb * 16);
            dma16(vg + (long)(jb + l) * 16, vT + jb * 16);
        }
        const char* sg = (const char*)(wsS + (long)bid * 8192);
        #pragma unroll
        for (int i = 0; i < 4; ++i) {
            int jb = wv * 256 + i * 64;
            int j = jb + l;
            int srcc = (j & ~15) | ((j & 15) ^ ((j >> 4) & 15));  // inverse swz15
            dma16(sg + (long)srcc * 16, St + jb * 16);
        }
    }

    // ---- global operand loads (early issue; q = own rows, Wt = tiny L2-hot,
    //      wsZ hoisted here so its latency hides under the u/phi phase)
    const float* qp = Q + base;
    short8 bq0 = gfrag_f32(qp, s, lg);
    short8 bq1 = gfrag_f32(qp, s, 4 + lg);
    const ushort* wt = Wt + (long)h * 4096;
    short8 aw[4][2];
    #pragma unroll
    for (int tf = 0; tf < 4; ++tf) {
        aw[tf][0] = gfrag_bf16(wt, tf * 16 + lr, lg, 64);
        aw[tf][1] = gfrag_bf16(wt, tf * 16 + lr, 4 + lg, 64);
    }
    float4 zv4[4], zn4[4];
    {
        const float* zp = wsZ + (long)bid * 128;
        #pragma unroll
        for (int tf = 0; tf < 4; ++tf) {
            zv4[tf] = *(const float4*)(zp + tf * 16 + lg * 4);
            zn4[tf] = *(const float4*)(zp + 64 + tf * 16 + lg * 4);
        }
    }

    // ---- u^T = mfma(A=Wt rows f, B=q col s) -> D[f][s]
    f32x4 uq[4];
    #pragma unroll
    for (int tf = 0; tf < 4; ++tf) uq[tf] = zero4();
    #pragma unroll
    for (int tf = 0; tf < 4; ++tf) {
        uq[tf] = mfma(aw[tf][0], bq0, uq[tf]);
        uq[tf] = mfma(aw[tf][1], bq1, uq[tf]);
    }

    // phi softmax over f for row s: in-lane(16) + xor16 + xor32
    float sp = 0.f, sn = 0.f;
    float pqp[4][4], pqn[4][4];
    #pragma unroll
    for (int tf = 0; tf < 4; ++tf)
        #pragma unroll
        for (int r = 0; r < 4; ++r) {
            pqp[tf][r] = __expf(uq[tf][r]);  sp += pqp[tf][r];
            pqn[tf][r] = __expf(-uq[tf][r]); sn += pqn[tf][r];
        }
    sp += __shfl_xor(sp, 16); sp += __shfl_xor(sp, 32);
    sn += __shfl_xor(sn, 16); sn += __shfl_xor(sn, 32);
    ushort4v phk[4], phkn[4];
    {
        float rp = 1.f / sp, rn = 1.f / sn;
        #pragma unroll
        for (int tf = 0; tf < 4; ++tf)
            #pragma unroll
            for (int r = 0; r < 4; ++r) {
                phk[tf][r]  = f2bf(pqp[tf][r] * rp);
                phkn[tf][r] = f2bf(pqn[tf][r] * rn);
            }
    }
    const float w = 1.f / (1.f + __expf(-Alpha[h]));

    // lden = max(phi . Z, EPS) from the hoisted Z registers
    float zd = 0.f;
    #pragma unroll
    for (int tf = 0; tf < 4; ++tf)
        #pragma unroll
        for (int r = 0; r < 4; ++r)
            zd += bf2f(phk[tf][r]) * (&zv4[tf].x)[r] + bf2f(phkn[tf][r]) * (&zn4[tf].x)[r];
    zd += __shfl_xor(zd, 16); zd += __shfl_xor(zd, 32);
    const float lden = fmaxf(zd, EPSf);

    __syncthreads();                                   // A: all DMAs landed

    // ---- scores^T = mfma(A=k rows t (LDS), B=q col s) -> D[t][s]
    f32x4 sc[4];
    #pragma unroll
    for (int tt = 0; tt < 4; ++tt) sc[tt] = zero4();
    __builtin_amdgcn_s_setprio(1);
    #pragma unroll
    for (int tt = 0; tt < 4; ++tt) {
        sc[tt] = mfma(ldfrag(kR, tt * 16 + lr, lg, 128, 7), bq0, sc[tt]);
        sc[tt] = mfma(ldfrag(kR, tt * 16 + lr, 4 + lg, 128, 7), bq1, sc[tt]);
    }
    __builtin_amdgcn_s_setprio(0);
    #pragma unroll
    for (int tt = 0; tt < 4; ++tt)
        #pragma unroll
        for (int r = 0; r < 4; ++r) sc[tt][r] *= SCALE;
    float m2;
    {
        float m01 = fmaxf(fmaxf(fmaxf(sc[0][0], sc[0][1]), fmaxf(sc[0][2], sc[0][3])),
                          fmaxf(fmaxf(sc[1][0], sc[1][1]), fmaxf(sc[1][2], sc[1][3])));
        float m23 = fmaxf(fmaxf(fmaxf(sc[2][0], sc[2][1]), fmaxf(sc[2][2], sc[2][3])),
                          fmaxf(fmaxf(sc[3][0], sc[3][1]), fmaxf(sc[3][2], sc[3][3])));
        m2 = fmaxf(m01, m23);
        m2 = fmaxf(m2, __shfl_xor(m2, 16));
        m2 = fmaxf(m2, __shfl_xor(m2, 32));
    }
    // compute exp, WRITE a-frags immediately (overlaps the shfl reduction),
    // then reduce the denominator
    float as = 0.f;
    ushort4v apk[4];
    #pragma unroll
    for (int tt = 0; tt < 4; ++tt)
        #pragma unroll
        for (int r = 0; r < 4; ++r) {
            float e = __expf(sc[tt][r] - m2);
            as += e;
            apk[tt][r] = f2bf(w * e);                  // bake w into numerator
        }
    #pragma unroll
    for (int tt = 0; tt < 4; ++tt)
        *(ushort4v*)(aAB + s * 128 + ((32 * tt + 8 * lg) ^ ((s & 7) << 4))) = apk[tt];
    as += __shfl_xor(as, 16); as += __shfl_xor(as, 32);
    const float sden = fmaxf(as, EPSf);
    const float inv = 1.f / fmaxf(w * sden + lden, EPSf);

    // ---- a@v MFMAs (vT last use); a frags own-wave rows -> no barrier
    f32x4 oacc[4];
    #pragma unroll
    for (int td = 0; td < 4; ++td) oacc[td] = zero4();
    short8 aa0 = ldfrag(aAB, s, lg, 128, 7);
    short8 aa1 = ldfrag(aAB, s, 4 + lg, 128, 7);
    __builtin_amdgcn_s_setprio(1);
    #pragma unroll
    for (int td = 0; td < 4; ++td) {
        oacc[td] = mfma(aa0, ldfrag(vT, td * 16 + lr, lg, 128, 7), oacc[td]);
        oacc[td] = mfma(aa1, ldfrag(vT, td * 16 + lr, 4 + lg, 128, 7), oacc[td]);
    }
    __builtin_amdgcn_s_setprio(0);

    __syncthreads();                                   // B: all kR+vT reads done

    // phi writes (overlay kR+vT region), packed 8B, own rows -> own-wave reads
    #pragma unroll
    for (int tf = 0; tf < 4; ++tf) {
        *(ushort4v*)(phiAB + s * 256 + ((32 * tf + 8 * lg) ^ ((s & 15) << 4))) = phk[tf];
        *(ushort4v*)(phiAB + s * 256 + ((128 + 32 * tf + 8 * lg) ^ ((s & 15) << 4))) = phkn[tf];
    }
    short8 pf[4];
    #pragma unroll
    for (int kc = 0; kc < 4; ++kc) pf[kc] = ldfrag(phiAB, s, kc * 4 + lg, 256, 15);
    __builtin_amdgcn_s_setprio(1);
    #pragma unroll
    for (int td = 0; td < 4; ++td)
        #pragma unroll
        for (int kc = 0; kc < 4; ++kc)
            oacc[td] = mfma(pf[kc], ldfrag(St, td * 16 + lr, kc * 4 + lg, 256, 15), oacc[td]);
    __builtin_amdgcn_s_setprio(0);

    // epilogue: broadcast inv from row-owner lane, store
    float* op = Out + base;
    #pragma unroll
    for (int r = 0; r < 4; ++r) {
        float invr = __shfl(inv, lg * 4 + r, 16);
        int sr = 16 * wv + lg * 4 + r;
        #pragma unroll
        for (int td = 0; td < 4; ++td)
            op[sr * 64 + td * 16 + lr] = oacc[td][r] * invr;
    }
}

// ---------------------------------------------------------------------------
extern "C" void kernel_launch(void* const* d_in, const int* in_sizes, int n_in,
                              void* d_out, int out_size, void* d_ws, size_t ws_size,
                              hipStream_t stream)
{
    const float* q     = (const float*)d_in[0];
    const float* k     = (const float*)d_in[1];
    const float* v     = (const float*)d_in[2];
    const float* W     = (const float*)d_in[3];
    const float* alpha = (const float*)d_in[4];
    float* out = (float*)d_out;

    // ws layout: wsS 33.5MB | wsZ 1MB | Wt 128KB | wsV 16.8MB | wsK 16.8MB
    ushort* wsSb = (ushort*)d_ws;
    float*  wsZ  = (float*)((char*)d_ws + (size_t)NBLK * F2 * Dc * 2);
    ushort* Wtb  = (ushort*)((char*)wsZ + (size_t)NBLK * F2 * 4);
    char*   wsV  = (char*)Wtb + (size_t)Hc * 4096 * 2;
    char*   wsK  = wsV + (size_t)NBLK * 8192;

    passW<<<Hc, 256, 0, stream>>>(W, Wtb);
    passA<<<NBLK, 256, 0, stream>>>(k, v, Wtb, wsSb, wsZ, wsV, wsK);
    passB<<<544, 256, 0, stream>>>((uint*)wsSb, wsZ);
    passC<<<NBLK, 256, 0, stream>>>(q, Wtb, alpha, wsSb, wsZ, wsV, wsK, out);
}

// Round 10
// 70.915 us; speedup vs baseline: 1.0059x; 1.0059x over previous
//
#include <hip/hip_runtime.h>
#include <hip/hip_bf16.h>
#include <math.h>

// BlockSoftmaxLinearHybrid: B=2,H=16,L=4096,D=64,F=64,S=64
constexpr int Hc = 16, Lc = 4096, Dc = 64;
constexpr int F2 = 128;
constexpr int NBLK = 2048;         // 32 bh * 64 tiles
constexpr float EPSf = 1e-6f;
constexpr float SCALE = 0.125f;    // D^-0.5

typedef short short8 __attribute__((ext_vector_type(8)));     // 8 bf16 MFMA A/B frag
typedef float f32x4 __attribute__((ext_vector_type(4)));      // MFMA C/D frag
typedef unsigned short ushort;
typedef unsigned int uint;
typedef ushort ushort4v __attribute__((ext_vector_type(4)));

__device__ inline ushort f2bf(float x) {           // native cvt (fuses to v_cvt_pk_bf16_f32)
    return __builtin_bit_cast(ushort, __float2bfloat16(x));
}
__device__ inline float bf2f(ushort h) {
    return __builtin_bit_cast(float, ((unsigned)h) << 16);
}
__device__ inline f32x4 zero4() { f32x4 z = {0.f, 0.f, 0.f, 0.f}; return z; }

__device__ inline f32x4 mfma(short8 a, short8 b, f32x4 c) {
    return __builtin_amdgcn_mfma_f32_16x16x32_bf16(a, b, c, 0, 0, 0);
}

// async 16B global->LDS DMA (per-lane global addr, wave-uniform LDS base + lane*16)
__device__ inline void dma16(const void* g, void* l) {
    __builtin_amdgcn_global_load_lds(
        (const __attribute__((address_space(1))) unsigned int*)g,
        (__attribute__((address_space(3))) unsigned int*)l, 16, 0, 0);
}

// LDS fragment read, XOR-swizzled 16B chunks (T2)
__device__ inline short8 ldfrag(const char* L, int row, int chunk, int rowbytes, int mask) {
    return *(const short8*)(L + row * rowbytes + ((chunk * 16) ^ ((row & mask) << 4)));
}

// Direct global frag: 8 consecutive fp32 at [row][chunk*8] of row-major [.][64] -> bf16
__device__ inline short8 gfrag_f32(const float* __restrict__ base, int row, int chunk) {
    const float4* p = (const float4*)(base + row * 64 + chunk * 8);
    float4 a = p[0], b = p[1];
    short8 r;
    r[0] = (short)f2bf(a.x); r[1] = (short)f2bf(a.y); r[2] = (short)f2bf(a.z); r[3] = (short)f2bf(a.w);
    r[4] = (short)f2bf(b.x); r[5] = (short)f2bf(b.y); r[6] = (short)f2bf(b.z); r[7] = (short)f2bf(b.w);
    return r;
}
// Direct global frag from bf16 row-major [.][rowlen]
__device__ inline short8 gfrag_bf16(const ushort* __restrict__ base, int row, int chunk, int rowlen) {
    return *(const short8*)(base + row * rowlen + chunk * 8);
}

// coalesced transpose stage: [64][64] fp32 -> dst[j][i] bf16 swz (mask 7)
__device__ inline void stage_tr(const float* __restrict__ src, char* dst, int t) {
    int j = t & 63, g = t >> 6;
    #pragma unroll
    for (int i = 0; i < 4; ++i) {
        int i0 = g * 4 + i * 16;
        ushort4v hv;
        #pragma unroll
        for (int jj = 0; jj < 4; ++jj) hv[jj] = f2bf(src[(i0 + jj) * 64 + j]);
        *(ushort4v*)(dst + j * 128 + ((2 * i0) ^ ((j & 7) << 4))) = hv;
    }
}

// ---------------------------------------------------------------------------
// passW: Wt[h][f][d] = bf16(W[h][d][f])
// ---------------------------------------------------------------------------
__global__ __launch_bounds__(256) void passW(const float* __restrict__ W,
                                             ushort* __restrict__ Wt)
{
    const int h = blockIdx.x, t = threadIdx.x;
    const int f = t & 63, g = t >> 6;
    const float* src = W + (long)h * 4096;
    ushort* dst = Wt + (long)h * 4096;
    #pragma unroll
    for (int i = 0; i < 16; ++i) {
        int d = g * 16 + i;
        dst[f * 64 + d] = f2bf(src[d * 64 + f]);
    }
}

// ---------------------------------------------------------------------------
// passA: phi(k); dSt[d][f] = v^T @ phi_k -> wsS bf16; dZ[f] -> wsZ fp32;
//        dump swizzled vT bytes -> wsV and swizzled k bf16 -> wsK
//        (passC DMAs both back, bit-identical). ONE barrier.
// ---------------------------------------------------------------------------
__global__ __launch_bounds__(256) void passA(const float* __restrict__ K,
                                             const float* __restrict__ V,
                                             const ushort* __restrict__ Wt,
                                             ushort* __restrict__ wsS,
                                             float* __restrict__ wsZ,
                                             char* __restrict__ wsV,
                                             char* __restrict__ wsK)
{
    __shared__ __align__(16) char lds[26624];
    char* vT = lds;                      // [64 d][64 s] swz7
    char* pT = lds + 8192;               // [128 f][64 s] swz7
    float* Zp = (float*)(lds + 24576);   // [4 wv][128 f]

    const int t = threadIdx.x, wv = t >> 6, l = t & 63, lr = l & 15, lg = l >> 4;
    const int bid = blockIdx.x, bh = bid >> 6, h = bh & (Hc - 1);
    const long base = (long)bh * (Lc * Dc) + (long)(bid & 63) * (64 * Dc);

    stage_tr(V + base, vT, t);

    const float* kp = K + base;
    const ushort* wt = Wt + (long)h * 4096;

    // u = k @ W : A = k rows (own-wave rows, global), B = Wt rows (global bf16)
    short8 ak0 = gfrag_f32(kp, 16 * wv + lr, lg);
    short8 ak1 = gfrag_f32(kp, 16 * wv + lr, 4 + lg);

    // dump k bf16 in swizzled byte order (passC DMAs linearly -> swz LDS, T21)
    {
        char* kd = wsK + (long)bid * 8192;
        const int srow = 16 * wv + lr;
        *(short8*)(kd + srow * 128 + ((lg * 16) ^ ((srow & 7) << 4))) = ak0;
        *(short8*)(kd + srow * 128 + (((4 + lg) * 16) ^ ((srow & 7) << 4))) = ak1;
    }

    f32x4 u0[4];
    #pragma unroll
    for (int tf = 0; tf < 4; ++tf) u0[tf] = zero4();
    #pragma unroll
    for (int tf = 0; tf < 4; ++tf) {
        u0[tf] = mfma(ak0, gfrag_bf16(wt, tf * 16 + lr, lg, 64), u0[tf]);
        u0[tf] = mfma(ak1, gfrag_bf16(wt, tf * 16 + lr, 4 + lg, 64), u0[tf]);
    }

    // dual softmax over f (no max-sub: softmax invariant, |u| small)
    float pp[4][4], pn[4][4];
    float zpa[4] = {0.f,0.f,0.f,0.f}, zna[4] = {0.f,0.f,0.f,0.f};
    #pragma unroll
    for (int r = 0; r < 4; ++r) {
        float sp = 0.f, sn = 0.f;
        #pragma unroll
        for (int tf = 0; tf < 4; ++tf) {
            pp[tf][r] = __expf(u0[tf][r]);  sp += pp[tf][r];
            pn[tf][r] = __expf(-u0[tf][r]); sn += pn[tf][r];
        }
        #pragma unroll
        for (int m = 1; m < 16; m <<= 1) { sp += __shfl_xor(sp, m, 16); sn += __shfl_xor(sn, m, 16); }
        float rp = 1.f / sp, rn = 1.f / sn;
        #pragma unroll
        for (int tf = 0; tf < 4; ++tf) {
            pp[tf][r] *= rp; pn[tf][r] *= rn;
            zpa[tf] += pp[tf][r]; zna[tf] += pn[tf][r];
        }
    }

    // packed phi_k^T writes: pT[f][s], 4 consecutive s -> ds_write_b64
    const int s0 = 16 * wv + lg * 4;
    #pragma unroll
    for (int tf = 0; tf < 4; ++tf) {
        int f = tf * 16 + lr;
        ushort4v hp, hn;
        #pragma unroll
        for (int r = 0; r < 4; ++r) { hp[r] = f2bf(pp[tf][r]); hn[r] = f2bf(pn[tf][r]); }
        *(ushort4v*)(pT + f * 128 + ((2 * s0) ^ ((f & 7) << 4))) = hp;
        int fn = 64 + f;
        *(ushort4v*)(pT + fn * 128 + ((2 * s0) ^ ((fn & 7) << 4))) = hn;
    }
    // Z partials (per wave)
    #pragma unroll
    for (int tf = 0; tf < 4; ++tf) {
        zpa[tf] += __shfl_xor(zpa[tf], 16); zpa[tf] += __shfl_xor(zpa[tf], 32);
        zna[tf] += __shfl_xor(zna[tf], 16); zna[tf] += __shfl_xor(zna[tf], 32);
    }
    if (l < 16) {
        #pragma unroll
        for (int tf = 0; tf < 4; ++tf) {
            Zp[wv * 128 + tf * 16 + lr]      = zpa[tf];
            Zp[wv * 128 + 64 + tf * 16 + lr] = zna[tf];
        }
    }
    __syncthreads();

    // dump swizzled vT bytes (bit-identical reuse by passC via DMA)
    {
        const short8* vs = (const short8*)vT;
        short8* vd = (short8*)(wsV + (long)bid * 8192);
        vd[t]       = vs[t];
        vd[t + 256] = vs[t + 256];
    }

    // dSt[d][f] = v^T @ phi_k
    short8 av0 = ldfrag(vT, 16 * wv + lr, lg, 128, 7);
    short8 av1 = ldfrag(vT, 16 * wv + lr, 4 + lg, 128, 7);
    f32x4 acc[8];
    #pragma unroll
    for (int tf = 0; tf < 8; ++tf) acc[tf] = zero4();
    __builtin_amdgcn_s_setprio(1);
    #pragma unroll
    for (int tf = 0; tf < 8; ++tf) {
        acc[tf] = mfma(av0, ldfrag(pT, tf * 16 + lr, lg, 128, 7), acc[tf]);
        acc[tf] = mfma(av1, ldfrag(pT, tf * 16 + lr, 4 + lg, 128, 7), acc[tf]);
    }
    __builtin_amdgcn_s_setprio(0);
    ushort* o = wsS + (long)bid * (F2 * Dc);
    #pragma unroll
    for (int tf = 0; tf < 8; ++tf)
        #pragma unroll
        for (int r = 0; r < 4; ++r) {
            int d = 16 * wv + lg * 4 + r;
            o[d * 128 + tf * 16 + lr] = f2bf(acc[tf][r]);
        }

    if (t < 128)
        wsZ[(long)bid * F2 + t] = Zp[t] + Zp[128 + t] + Zp[256 + t] + Zp[384 + t];
}

// ---------------------------------------------------------------------------
// passB: exclusive prefix over n per bh. 2048 wave-slices (4B/lane), all 64
// tile-loads batched in flight. grid = 512 S-blocks + 32 Z-blocks.
// ---------------------------------------------------------------------------
__global__ __launch_bounds__(256) void passB(uint* __restrict__ wsSu,
                                             float* __restrict__ wsZ)
{
    const int t = threadIdx.x;
    if (blockIdx.x >= 512) {                 // Z prefix
        const int bh = blockIdx.x - 512;
        if (t < 128) {
            float zc = 0.f, zb[32];
            #pragma unroll
            for (int h2 = 0; h2 < 2; ++h2) {
                float* zp = wsZ + ((long)bh * 64 + h2 * 32) * 128 + t;
                #pragma unroll
                for (int i = 0; i < 32; ++i) zb[i] = zp[i * 128];
                #pragma unroll
                for (int i = 0; i < 32; ++i) { float x = zb[i]; zp[i * 128] = zc; zc += x; }
            }
        }
        return;
    }
    const int bh = blockIdx.x >> 4;
    const int slice = (blockIdx.x & 15) * 4 + (t >> 6);    // 0..63 per bh
    const int lane = t & 63;
    uint* p = wsSu + (long)bh * 64 * 4096 + slice * 64 + lane;
    uint buf[64];
    #pragma unroll
    for (int i = 0; i < 64; ++i) buf[i] = p[i * 4096];
    float c0 = 0.f, c1 = 0.f;
    #pragma unroll
    for (int i = 0; i < 64; ++i) {
        uint x = buf[i];
        uint pc = ((uint)f2bf(c1) << 16) | (uint)f2bf(c0);
        p[i * 4096] = pc;
        c0 += bf2f((ushort)(x & 0xffffu));
        c1 += bf2f((ushort)(x >> 16));
    }
}

// ---------------------------------------------------------------------------
// passC: 32K LDS / 5 blocks/CU. kR region is triple-used: kR (scores, shared)
// -> barrier A2 -> aAB (wave-private a frags) -> phi halves (wave-private,
// sequential f<64 then f>=64). vT/St DMA'd; q own-row frags; Wt L2-hot.
// ---------------------------------------------------------------------------
__global__ __launch_bounds__(256, 5) void passC(const float* __restrict__ Q,
                                                const ushort* __restrict__ Wt,
                                                const float* __restrict__ Alpha,
                                                const ushort* __restrict__ wsS,
                                                const float* __restrict__ wsZ,
                                                const char* __restrict__ wsV,
                                                const char* __restrict__ wsK,
                                                float* __restrict__ Out)
{
    __shared__ __align__(16) char lds[32768];
    char* kR   = lds;                    // 8K [64 t][64 d] swz7 (DMA; shared, dies at A2)
    char* aAB  = lds;                    // 8K overlay: [64 s][64 t] swz7 (wave-private)
    char* phiH = lds;                    // 8K overlay: [64 s][64 f-half] swz7 (wave-private)
    char* vT   = lds + 8192;             // 8K [64 d][64 t] swz7 (DMA; shared)
    char* St   = lds + 16384;            // 16K [64 d][128 f] swz15 (DMA; live to end)

    const int t = threadIdx.x, wv = t >> 6, l = t & 63, lr = l & 15, lg = l >> 4;
    const int bid = blockIdx.x, bh = bid >> 6, h = bh & (Hc - 1);
    const long base = (long)bh * (Lc * Dc) + (long)(bid & 63) * (64 * Dc);
    const int s = 16 * wv + lr;          // this lane's owned row

    // ---- async DMA staging (issue first; drains at barrier A)
    {
        const char* kg = wsK + (long)bid * 8192;
        const char* vg = wsV + (long)bid * 8192;
        #pragma unroll
        for (int i = 0; i < 2; ++i) {
            int jb = wv * 128 + i * 64;
            dma16(kg + (long)(jb + l) * 16, kR + jb * 16);
            dma16(vg + (long)(jb + l) * 16, vT + jb * 16);
        }
        const char* sg = (const char*)(wsS + (long)bid * 8192);
        #pragma unroll
        for (int i = 0; i < 4; ++i) {
            int jb = wv * 256 + i * 64;
            int j = jb + l;
            int srcc = (j & ~15) | ((j & 15) ^ ((j >> 4) & 15));  // inverse swz15
            dma16(sg + (long)srcc * 16, St + jb * 16);
        }
    }

    // ---- global operand loads (early issue; q = own rows, Wt = tiny L2-hot,
    //      wsZ hoisted so its latency hides under the u/phi phase)
    const float* qp = Q + base;
    short8 bq0 = gfrag_f32(qp, s, lg);
    short8 bq1 = gfrag_f32(qp, s, 4 + lg);
    const ushort* wt = Wt + (long)h * 4096;
    short8 aw[4][2];
    #pragma unroll
    for (int tf = 0; tf < 4; ++tf) {
        aw[tf][0] = gfrag_bf16(wt, tf * 16 + lr, lg, 64);
        aw[tf][1] = gfrag_bf16(wt, tf * 16 + lr, 4 + lg, 64);
    }
    float4 zv4[4], zn4[4];
    {
        const float* zp = wsZ + (long)bid * 128;
        #pragma unroll
        for (int tf = 0; tf < 4; ++tf) {
            zv4[tf] = *(const float4*)(zp + tf * 16 + lg * 4);
            zn4[tf] = *(const float4*)(zp + 64 + tf * 16 + lg * 4);
        }
    }

    // ---- u^T = mfma(A=Wt rows f, B=q col s) -> D[f][s]
    f32x4 uq[4];
    #pragma unroll
    for (int tf = 0; tf < 4; ++tf) uq[tf] = zero4();
    #pragma unroll
    for (int tf = 0; tf < 4; ++tf) {
        uq[tf] = mfma(aw[tf][0], bq0, uq[tf]);
        uq[tf] = mfma(aw[tf][1], bq1, uq[tf]);
    }

    // phi softmax over f for row s: in-lane(16) + xor16 + xor32
    float sp = 0.f, sn = 0.f;
    float pqp[4][4], pqn[4][4];
    #pragma unroll
    for (int tf = 0; tf < 4; ++tf)
        #pragma unroll
        for (int r = 0; r < 4; ++r) {
            pqp[tf][r] = __expf(uq[tf][r]);  sp += pqp[tf][r];
            pqn[tf][r] = __expf(-uq[tf][r]); sn += pqn[tf][r];
        }
    sp += __shfl_xor(sp, 16); sp += __shfl_xor(sp, 32);
    sn += __shfl_xor(sn, 16); sn += __shfl_xor(sn, 32);
    ushort4v phk[4], phkn[4];
    {
        float rp = 1.f / sp, rn = 1.f / sn;
        #pragma unroll
        for (int tf = 0; tf < 4; ++tf)
            #pragma unroll
            for (int r = 0; r < 4; ++r) {
                phk[tf][r]  = f2bf(pqp[tf][r] * rp);
                phkn[tf][r] = f2bf(pqn[tf][r] * rn);
            }
    }
    const float w = 1.f / (1.f + __expf(-Alpha[h]));

    // lden = max(phi . Z, EPS) from the hoisted Z registers
    float zd = 0.f;
    #pragma unroll
    for (int tf = 0; tf < 4; ++tf)
        #pragma unroll
        for (int r = 0; r < 4; ++r)
            zd += bf2f(phk[tf][r]) * (&zv4[tf].x)[r] + bf2f(phkn[tf][r]) * (&zn4[tf].x)[r];
    zd += __shfl_xor(zd, 16); zd += __shfl_xor(zd, 32);
    const float lden = fmaxf(zd, EPSf);

    __syncthreads();                                   // A: all DMAs landed

    // ---- scores^T = mfma(A=k rows t (LDS), B=q col s) -> D[t][s]
    f32x4 sc[4];
    #pragma unroll
    for (int tt = 0; tt < 4; ++tt) sc[tt] = zero4();
    __builtin_amdgcn_s_setprio(1);
    #pragma unroll
    for (int tt = 0; tt < 4; ++tt) {
        sc[tt] = mfma(ldfrag(kR, tt * 16 + lr, lg, 128, 7), bq0, sc[tt]);
        sc[tt] = mfma(ldfrag(kR, tt * 16 + lr, 4 + lg, 128, 7), bq1, sc[tt]);
    }
    __builtin_amdgcn_s_setprio(0);
    #pragma unroll
    for (int tt = 0; tt < 4; ++tt)
        #pragma unroll
        for (int r = 0; r < 4; ++r) sc[tt][r] *= SCALE;
    float m2;
    {
        float m01 = fmaxf(fmaxf(fmaxf(sc[0][0], sc[0][1]), fmaxf(sc[0][2], sc[0][3])),
                          fmaxf(fmaxf(sc[1][0], sc[1][1]), fmaxf(sc[1][2], sc[1][3])));
        float m23 = fmaxf(fmaxf(fmaxf(sc[2][0], sc[2][1]), fmaxf(sc[2][2], sc[2][3])),
                          fmaxf(fmaxf(sc[3][0], sc[3][1]), fmaxf(sc[3][2], sc[3][3])));
        m2 = fmaxf(m01, m23);
        m2 = fmaxf(m2, __shfl_xor(m2, 16));
        m2 = fmaxf(m2, __shfl_xor(m2, 32));
    }
    float as = 0.f;
    ushort4v apk[4];
    #pragma unroll
    for (int tt = 0; tt < 4; ++tt)
        #pragma unroll
        for (int r = 0; r < 4; ++r) {
            float e = __expf(sc[tt][r] - m2);
            as += e;
            apk[tt][r] = f2bf(w * e);                  // bake w into numerator
        }
    as += __shfl_xor(as, 16); as += __shfl_xor(as, 32);
    const float sden = fmaxf(as, EPSf);
    const float inv = 1.f / fmaxf(w * sden + lden, EPSf);

    __syncthreads();                                   // A2: all waves done with kR

    // a frags into the freed kR region (wave-private rows); own-wave round trip
    #pragma unroll
    for (int tt = 0; tt < 4; ++tt)
        *(ushort4v*)(aAB + s * 128 + ((32 * tt + 8 * lg) ^ ((s & 7) << 4))) = apk[tt];
    short8 aa0 = ldfrag(aAB, s, lg, 128, 7);
    short8 aa1 = ldfrag(aAB, s, 4 + lg, 128, 7);

    // ---- a@v MFMAs (vT last use)
    f32x4 oacc[4];
    #pragma unroll
    for (int td = 0; td < 4; ++td) oacc[td] = zero4();
    __builtin_amdgcn_s_setprio(1);
    #pragma unroll
    for (int td = 0; td < 4; ++td) {
        oacc[td] = mfma(aa0, ldfrag(vT, td * 16 + lr, lg, 128, 7), oacc[td]);
        oacc[td] = mfma(aa1, ldfrag(vT, td * 16 + lr, 4 + lg, 128, 7), oacc[td]);
    }
    __builtin_amdgcn_s_setprio(0);

    // ---- phi@S in two halves over the SAME wave-private region (no barrier):
    // half P: f in [0,64)
    #pragma unroll
    for (int tf = 0; tf < 4; ++tf)
        *(ushort4v*)(phiH + s * 128 + ((32 * tf + 8 * lg) ^ ((s & 7) << 4))) = phk[tf];
    {
        short8 pf0 = ldfrag(phiH, s, lg, 128, 7);
        short8 pf1 = ldfrag(phiH, s, 4 + lg, 128, 7);
        __builtin_amdgcn_s_setprio(1);
        #pragma unroll
        for (int td = 0; td < 4; ++td) {
            oacc[td] = mfma(pf0, ldfrag(St, td * 16 + lr, lg, 256, 15), oacc[td]);
            oacc[td] = mfma(pf1, ldfrag(St, td * 16 + lr, 4 + lg, 256, 15), oacc[td]);
        }
        __builtin_amdgcn_s_setprio(0);
    }
    // half N: f in [64,128)
    #pragma unroll
    for (int tf = 0; tf < 4; ++tf)
        *(ushort4v*)(phiH + s * 128 + ((32 * tf + 8 * lg) ^ ((s & 7) << 4))) = phkn[tf];
    {
        short8 pn0 = ldfrag(phiH, s, lg, 128, 7);
        short8 pn1 = ldfrag(phiH, s, 4 + lg, 128, 7);
        __builtin_amdgcn_s_setprio(1);
        #pragma unroll
        for (int td = 0; td < 4; ++td) {
            oacc[td] = mfma(pn0, ldfrag(St, td * 16 + lr, 8 + lg, 256, 15), oacc[td]);
            oacc[td] = mfma(pn1, ldfrag(St, td * 16 + lr, 12 + lg, 256, 15), oacc[td]);
        }
        __builtin_amdgcn_s_setprio(0);
    }

    // epilogue: broadcast inv from row-owner lane, store
    float* op = Out + base;
    #pragma unroll
    for (int r = 0; r < 4; ++r) {
        float invr = __shfl(inv, lg * 4 + r, 16);
        int sr = 16 * wv + lg * 4 + r;
        #pragma unroll
        for (int td = 0; td < 4; ++td)
            op[sr * 64 + td * 16 + lr] = oacc[td][r] * invr;
    }
}

// ---------------------------------------------------------------------------
extern "C" void kernel_launch(void* const* d_in, const int* in_sizes, int n_in,
                              void* d_out, int out_size, void* d_ws, size_t ws_size,
                              hipStream_t stream)
{
    const float* q     = (const float*)d_in[0];
    const float* k     = (const float*)d_in[1];
    const float* v     = (const float*)d_in[2];
    const float* W     = (const float*)d_in[3];
    const float* alpha = (const float*)d_in[4];
    float* out = (float*)d_out;

    // ws layout: wsS 33.5MB | wsZ 1MB | Wt 128KB | wsV 16.8MB | wsK 16.8MB
    ushort* wsSb = (ushort*)d_ws;
    float*  wsZ  = (float*)((char*)d_ws + (size_t)NBLK * F2 * Dc * 2);
    ushort* Wtb  = (ushort*)((char*)wsZ + (size_t)NBLK * F2 * 4);
    char*   wsV  = (char*)Wtb + (size_t)Hc * 4096 * 2;
    char*   wsK  = wsV + (size_t)NBLK * 8192;

    passW<<<Hc, 256, 0, stream>>>(W, Wtb);
    passA<<<NBLK, 256, 0, stream>>>(k, v, Wtb, wsSb, wsZ, wsV, wsK);
    passB<<<544, 256, 0, stream>>>((uint*)wsSb, wsZ);
    passC<<<NBLK, 256, 0, stream>>>(q, Wtb, alpha, wsSb, wsZ, wsV, wsK, out);
}